// Round 8
// baseline (236.479 us; speedup 1.0000x reference)
//
#include <hip/hip_runtime.h>
#include <hip/hip_bf16.h>
#include <stdint.h>

// (B, L, QD, H, D) = (2, 2048, 1024, 16, 64)
#define BB 2
#define LL 2048
#define QDIM 1024
#define NH 16
#define HD 64

using bf16x8 = __attribute__((ext_vector_type(8))) __bf16;
using bf16x2 = __attribute__((ext_vector_type(2))) __bf16;
using f32x4  = __attribute__((ext_vector_type(4))) float;
using u16x8  = __attribute__((ext_vector_type(8))) unsigned short;
using u32x2  = __attribute__((ext_vector_type(2))) uint32_t;

__device__ __forceinline__ unsigned short f2bf(float f) {
  return __builtin_bit_cast(unsigned short, (__bf16)f);   // HW v_cvt (RNE)
}
__device__ __forceinline__ float bf2f(unsigned short h) {
  uint32_t u = ((uint32_t)h) << 16;
  return __builtin_bit_cast(float, u);
}
__device__ __forceinline__ uint32_t pkbf2(float a, float b) {
  bf16x2 v = { (__bf16)a, (__bf16)b };
  return __builtin_bit_cast(uint32_t, v);
}

__device__ __forceinline__ void gload_lds16(const void* g, void* l) {
  __builtin_amdgcn_global_load_lds((__attribute__((address_space(1))) void*)g,
                                   (__attribute__((address_space(3))) void*)l,
                                   16, 0, 0);
}

// ---------------- fp32 -> bf16 cast ----------------
__global__ __launch_bounds__(256) void k_cast_bf16(const float* __restrict__ in,
                                                   unsigned short* __restrict__ out, int n) {
  int i = (blockIdx.x * 256 + threadIdx.x) * 8;
  if (i >= n) return;
  float4 a = *reinterpret_cast<const float4*>(in + i);
  float4 b = *reinterpret_cast<const float4*>(in + i + 4);
  u16x8 o;
  o[0] = f2bf(a.x); o[1] = f2bf(a.y); o[2] = f2bf(a.z); o[3] = f2bf(a.w);
  o[4] = f2bf(b.x); o[5] = f2bf(b.y); o[6] = f2bf(b.z); o[7] = f2bf(b.w);
  *reinterpret_cast<u16x8*>(out + i) = o;
}

// ------- merged QKV GEMM: C = xb * Wall^T, 128x128 tile, BK=32, LDS double-buffered -------
// Wall rows: [0,1024)=Wq, [1024,2048)=Wk, [2048,3072)=Wv
// cols<2048 -> qk[row*2048+col] bf16 ; cols>=2048 -> vT[(bh*64+d)*2048 + l] transposed
__global__ __launch_bounds__(256) void k_gemm_qkv(const unsigned short* __restrict__ A,
                                                  const unsigned short* __restrict__ Bw,
                                                  unsigned short* __restrict__ qk,
                                                  unsigned short* __restrict__ vT) {
  __shared__ unsigned short As[2][128 * 32];
  __shared__ unsigned short Bs[2][128 * 32];
  const int t = threadIdx.x;
  const int lane = t & 63, w = t >> 6;
  const int wm = w >> 1, wn = w & 1;
  const int g = lane >> 4, r16 = lane & 15;
  const size_t am0 = (size_t)blockIdx.x * 128;
  const size_t bn0 = (size_t)blockIdx.y * 128;
  const int K = 1024;

  f32x4 acc[4][4] = {};

  const int o0 = t * 16, row0 = o0 >> 6, cb0 = o0 & 63;
  const int o1 = 4096 + t * 16, row1 = o1 >> 6, cb1 = o1 & 63;

  // prologue: stage tile 0 into buf 0
  gload_lds16(A  + (am0 + row0) * K + (cb0 >> 1), (char*)&As[0][0] + o0);
  gload_lds16(A  + (am0 + row1) * K + (cb1 >> 1), (char*)&As[0][0] + o1);
  gload_lds16(Bw + (bn0 + row0) * K + (cb0 >> 1), (char*)&Bs[0][0] + o0);
  gload_lds16(Bw + (bn0 + row1) * K + (cb1 >> 1), (char*)&Bs[0][0] + o1);
  __syncthreads();

  for (int kb = 0; kb < K; kb += 32) {
    const int cur = (kb >> 5) & 1;
    if (kb + 32 < K) {
      const int nxt = cur ^ 1;
      gload_lds16(A  + (am0 + row0) * K + kb + 32 + (cb0 >> 1), (char*)&As[nxt][0] + o0);
      gload_lds16(A  + (am0 + row1) * K + kb + 32 + (cb1 >> 1), (char*)&As[nxt][0] + o1);
      gload_lds16(Bw + (bn0 + row0) * K + kb + 32 + (cb0 >> 1), (char*)&Bs[nxt][0] + o0);
      gload_lds16(Bw + (bn0 + row1) * K + kb + 32 + (cb1 >> 1), (char*)&Bs[nxt][0] + o1);
    }
    bf16x8 af[4], bfr[4];
#pragma unroll
    for (int i = 0; i < 4; ++i)
      af[i] = *reinterpret_cast<const bf16x8*>((const char*)&As[cur][0] + (wm * 64 + i * 16 + r16) * 64 + g * 16);
#pragma unroll
    for (int j = 0; j < 4; ++j)
      bfr[j] = *reinterpret_cast<const bf16x8*>((const char*)&Bs[cur][0] + (wn * 64 + j * 16 + r16) * 64 + g * 16);
#pragma unroll
    for (int i = 0; i < 4; ++i)
#pragma unroll
      for (int j = 0; j < 4; ++j)
        acc[i][j] = __builtin_amdgcn_mfma_f32_16x16x32_bf16(af[i], bfr[j], acc[i][j], 0, 0, 0);
    __syncthreads();   // next tile staged + all waves done reading cur
  }

#pragma unroll
  for (int i = 0; i < 4; ++i)
#pragma unroll
    for (int j = 0; j < 4; ++j) {
      size_t row = am0 + wm * 64 + i * 16 + g * 4;
      int col = (int)bn0 + wn * 64 + j * 16 + r16;
      if (col < 2048) {
#pragma unroll
        for (int r = 0; r < 4; ++r) qk[(row + r) * 2048 + col] = f2bf(acc[i][j][r]);
      } else {
        int e = col - 2048, h = e >> 6, d = e & 63;
        int b = (int)(row >> 11), l2 = (int)(row & 2047);
        ushort4 pk;
        pk.x = f2bf(acc[i][j][0]); pk.y = f2bf(acc[i][j][1]);
        pk.z = f2bf(acc[i][j][2]); pk.w = f2bf(acc[i][j][3]);
        *reinterpret_cast<ushort4*>(vT + ((size_t)(b * 16 + h) * 64 + d) * 2048 + l2) = pk;
      }
    }
}

// ------- proj GEMM: out = ob * Wproj^T + bias, 64x128 tile, LDS double-buffered -------
__global__ __launch_bounds__(256) void k_gemm_proj(const unsigned short* __restrict__ A,
                                                   const unsigned short* __restrict__ Bw,
                                                   float* __restrict__ Cf,
                                                   const float* __restrict__ bias) {
  __shared__ unsigned short As[2][64 * 32];
  __shared__ unsigned short Bs[2][128 * 32];
  const int t = threadIdx.x;
  const int lane = t & 63, w = t >> 6;
  const int wm = w >> 1, wn = w & 1;
  const int g = lane >> 4, r16 = lane & 15;
  const size_t am0 = (size_t)blockIdx.x * 64;
  const size_t bn0 = (size_t)blockIdx.y * 128;
  const int K = 1024;

  f32x4 acc[2][4] = {};

  const int oa = t * 16, rowa = oa >> 6, cba = oa & 63;
  const int ob0 = t * 16, rowb0 = ob0 >> 6, cbb0 = ob0 & 63;
  const int ob1 = 4096 + t * 16, rowb1 = ob1 >> 6, cbb1 = ob1 & 63;

  gload_lds16(A  + (am0 + rowa)  * K + (cba  >> 1), (char*)&As[0][0] + oa);
  gload_lds16(Bw + (bn0 + rowb0) * K + (cbb0 >> 1), (char*)&Bs[0][0] + ob0);
  gload_lds16(Bw + (bn0 + rowb1) * K + (cbb1 >> 1), (char*)&Bs[0][0] + ob1);
  __syncthreads();

  for (int kb = 0; kb < K; kb += 32) {
    const int cur = (kb >> 5) & 1;
    if (kb + 32 < K) {
      const int nxt = cur ^ 1;
      gload_lds16(A  + (am0 + rowa)  * K + kb + 32 + (cba  >> 1), (char*)&As[nxt][0] + oa);
      gload_lds16(Bw + (bn0 + rowb0) * K + kb + 32 + (cbb0 >> 1), (char*)&Bs[nxt][0] + ob0);
      gload_lds16(Bw + (bn0 + rowb1) * K + kb + 32 + (cbb1 >> 1), (char*)&Bs[nxt][0] + ob1);
    }
    bf16x8 af[2], bfr[4];
#pragma unroll
    for (int i = 0; i < 2; ++i)
      af[i] = *reinterpret_cast<const bf16x8*>((const char*)&As[cur][0] + (wm * 32 + i * 16 + r16) * 64 + g * 16);
#pragma unroll
    for (int j = 0; j < 4; ++j)
      bfr[j] = *reinterpret_cast<const bf16x8*>((const char*)&Bs[cur][0] + (wn * 64 + j * 16 + r16) * 64 + g * 16);
#pragma unroll
    for (int i = 0; i < 2; ++i)
#pragma unroll
      for (int j = 0; j < 4; ++j)
        acc[i][j] = __builtin_amdgcn_mfma_f32_16x16x32_bf16(af[i], bfr[j], acc[i][j], 0, 0, 0);
    __syncthreads();
  }

#pragma unroll
  for (int i = 0; i < 2; ++i)
#pragma unroll
    for (int j = 0; j < 4; ++j) {
      size_t row = am0 + wm * 32 + i * 16 + g * 4;
      int col = (int)bn0 + wn * 64 + j * 16 + r16;
#pragma unroll
      for (int r = 0; r < 4; ++r) Cf[(row + r) * 1024 + col] = acc[i][j][r] + bias[col];
    }
}

// ---------------- per-head RMSNorm + RoPE, in place on qk (stride 2048) ----------------
// q additionally pre-scaled by 0.125*log2(e) so flash softmax runs in exp2 domain.
__global__ __launch_bounds__(256) void k_norm_rope(unsigned short* __restrict__ qkbuf,
                                                   const float* __restrict__ pe,
                                                   const float* __restrict__ qs,
                                                   const float* __restrict__ ks) {
  const float S2 = 0.125f * 1.44269504f;
  const int row = blockIdx.x;
  const int l = row & (LL - 1);
  const int t = threadIdx.x, w = t >> 6, lane = t & 63;
  const int hgrp = lane >> 5, dp = lane & 31;
  const size_t base = (size_t)row * 2048;
  const float4 pev = *reinterpret_cast<const float4*>(pe + ((size_t)l * 32 + dp) * 4);
  const float2 qsv0 = *reinterpret_cast<const float2*>(qs + dp * 2);
  const float2 ksv = *reinterpret_cast<const float2*>(ks + dp * 2);
  const float2 qsv = { qsv0.x * S2, qsv0.y * S2 };

#pragma unroll
  for (int pass = 0; pass < 4; ++pass) {
    const int isK = pass >> 1;
    const int h = w * 4 + (pass & 1) * 2 + hgrp;
    unsigned short* p = qkbuf + base + isK * 1024 + h * 64 + dp * 2;
    uint32_t v = *reinterpret_cast<uint32_t*>(p);
    float xe = bf2f((unsigned short)(v & 0xffff)), xo = bf2f((unsigned short)(v >> 16));
    float s = xe * xe + xo * xo;
#pragma unroll
    for (int mk = 1; mk < 32; mk <<= 1) s += __shfl_xor(s, mk);
    float rr = rsqrtf(s * (1.0f / 64.0f) + 1e-6f);
    float sx = isK ? ksv.x : qsv.x, sy = isK ? ksv.y : qsv.y;
    float ne = xe * rr * sx, no = xo * rr * sy;
    float oe = pev.x * ne + pev.y * no;
    float oo = pev.z * ne + pev.w * no;
    *reinterpret_cast<uint32_t*>(p) = (uint32_t)f2bf(oe) | ((uint32_t)f2bf(oo) << 16);
  }
}

// ---- flash attention: swapped operands, 2 q-streams/wave, LDS K/V 2-phase, exp2/defer-max ----
// grid 512 (XCD-swizzled), 4 waves; wave w: streams j=0,1 cover q-rows lt*128 + j*64 + w*16.
// Shared ka/va LDS fragment reads feed BOTH streams' MFMAs (halves LDS-read per q-row).
__global__ __launch_bounds__(256, 2) void k_flash(const unsigned short* __restrict__ qkbuf,
                                                  const unsigned short* __restrict__ vT,
                                                  unsigned short* __restrict__ ob) {
  __shared__ unsigned short Ktile[2][64 * 64];     // 16KB dbuf K
  __shared__ unsigned short Vtile[2][64 * 64];     // 16KB dbuf V^T
  __shared__ unsigned short Plds[4][2][16 * 64];   // 16KB per-wave per-stream P
  const int t = threadIdx.x, w = t >> 6, lane = t & 63;
  const int g = lane >> 4, r16 = lane & 15;
  const int id = blockIdx.x;                        // 0..511
  const int bh = (id & 7) + (((id >> 3) & 3) << 3); // all 16 l-tiles of a bh on one XCD
  const int lt = id >> 5;                           // 0..15
  const int b = bh >> 4, h = bh & 15;
  const int l0 = lt * 128 + w * 16;
  const size_t qkb = (size_t)b * LL * 2048;
  const unsigned short* Qp = qkbuf + qkb + (size_t)(l0 + r16) * 2048 + h * 64;
  const unsigned short* Kbase = qkbuf + qkb + 1024 + h * 64;
  const unsigned short* Vbase = vT + (size_t)bh * 64 * 2048;

  bf16x8 qf[2][2];
  qf[0][0] = *reinterpret_cast<const bf16x8*>(Qp + g * 8);
  qf[0][1] = *reinterpret_cast<const bf16x8*>(Qp + 32 + g * 8);
  qf[1][0] = *reinterpret_cast<const bf16x8*>(Qp + (size_t)64 * 2048 + g * 8);
  qf[1][1] = *reinterpret_cast<const bf16x8*>(Qp + (size_t)64 * 2048 + 32 + g * 8);

  f32x4 oacc[2][4] = {};
  float m[2] = {-1e30f, -1e30f}, lsum[2] = {0.f, 0.f};

  char* Pw0 = (char*)&Plds[w][0][0];
  char* Pw1 = (char*)&Plds[w][1][0];
  const int pswz = (r16 & 7) << 4;
  const int prow = r16 * 128;
  const int wr0 = prow + ((0 * 32 + g * 8) ^ pswz);
  const int wr1 = prow + ((1 * 32 + g * 8) ^ pswz);
  const int wr2 = prow + ((2 * 32 + g * 8) ^ pswz);
  const int wr3 = prow + ((3 * 32 + g * 8) ^ pswz);
  const int rd0 = prow + ((g * 16) ^ pswz);
  const int rd1 = prow + ((64 + g * 16) ^ pswz);

  const int so0 = t * 16, sr0 = so0 >> 7, sl0 = (so0 & 127) ^ ((sr0 & 7) << 4);
  const int so1 = 4096 + t * 16, sr1 = so1 >> 7, sl1 = (so1 & 127) ^ ((sr1 & 7) << 4);

  gload_lds16(Kbase + (size_t)sr0 * 2048 + (sl0 >> 1), (char*)&Ktile[0][0] + so0);
  gload_lds16(Kbase + (size_t)sr1 * 2048 + (sl1 >> 1), (char*)&Ktile[0][0] + so1);
  gload_lds16(Vbase + (size_t)sr0 * 2048 + (sl0 >> 1), (char*)&Vtile[0][0] + so0);
  gload_lds16(Vbase + (size_t)sr1 * 2048 + (sl1 >> 1), (char*)&Vtile[0][0] + so1);
  __syncthreads();

  const int kswz = (r16 & 7) << 4;

  for (int kt = 0; kt < LL; kt += 64) {
    const int cur = (kt >> 6) & 1;
    if (kt + 64 < LL) {
      const int nxt = cur ^ 1;
      gload_lds16(Kbase + (size_t)(kt + 64 + sr0) * 2048 + (sl0 >> 1), (char*)&Ktile[nxt][0] + so0);
      gload_lds16(Kbase + (size_t)(kt + 64 + sr1) * 2048 + (sl1 >> 1), (char*)&Ktile[nxt][0] + so1);
      gload_lds16(Vbase + (size_t)sr0 * 2048 + kt + 64 + (sl0 >> 1), (char*)&Vtile[nxt][0] + so0);
      gload_lds16(Vbase + (size_t)sr1 * 2048 + kt + 64 + (sl1 >> 1), (char*)&Vtile[nxt][0] + so1);
    }
    const char* Kt = (const char*)&Ktile[cur][0];
    const char* Vt = (const char*)&Vtile[cur][0];

    // ---- QK^T both streams: shared ka reads, 16 MFMA ----
    f32x4 s[2][4];
#pragma unroll
    for (int kb = 0; kb < 4; ++kb) {
      const char* kp = Kt + (kb * 16 + r16) * 128;
      bf16x8 ka0 = *reinterpret_cast<const bf16x8*>(kp + ((g * 16) ^ kswz));
      bf16x8 ka1 = *reinterpret_cast<const bf16x8*>(kp + ((64 + g * 16) ^ kswz));
#pragma unroll
      for (int j = 0; j < 2; ++j) {
        f32x4 z = {};
        z = __builtin_amdgcn_mfma_f32_16x16x32_bf16(ka0, qf[j][0], z, 0, 0, 0);
        z = __builtin_amdgcn_mfma_f32_16x16x32_bf16(ka1, qf[j][1], z, 0, 0, 0);
        s[j][kb] = z;
      }
    }
    // ---- online softmax per stream (exp2 domain, defer-max) ----
#pragma unroll
    for (int j = 0; j < 2; ++j) {
      float p[16];
#pragma unroll
      for (int kb = 0; kb < 4; ++kb)
#pragma unroll
        for (int r = 0; r < 4; ++r) p[kb * 4 + r] = s[j][kb][r];
      float t0 = fmaxf(fmaxf(p[0], p[1]), p[2]);
      float t1 = fmaxf(fmaxf(p[3], p[4]), p[5]);
      float t2 = fmaxf(fmaxf(p[6], p[7]), p[8]);
      float t3 = fmaxf(fmaxf(p[9], p[10]), p[11]);
      float t4 = fmaxf(fmaxf(p[12], p[13]), p[14]);
      float tm = fmaxf(fmaxf(fmaxf(t0, t1), t2), fmaxf(fmaxf(t3, t4), p[15]));
      tm = fmaxf(tm, __shfl_xor(tm, 16));
      tm = fmaxf(tm, __shfl_xor(tm, 32));
      if (!__all(tm <= m[j] + 11.0f)) {
        float nm = fmaxf(m[j], tm);
        float alpha = __builtin_exp2f(m[j] - nm);
        lsum[j] *= alpha;
#pragma unroll
        for (int dt = 0; dt < 4; ++dt) oacc[j][dt] *= alpha;
        m[j] = nm;
      }
#pragma unroll
      for (int i = 0; i < 16; ++i) p[i] = __builtin_exp2f(p[i] - m[j]);
      float a0 = (p[0] + p[1]) + (p[2] + p[3]);
      float a1 = (p[4] + p[5]) + (p[6] + p[7]);
      float a2 = (p[8] + p[9]) + (p[10] + p[11]);
      float a3 = (p[12] + p[13]) + (p[14] + p[15]);
      float ts = (a0 + a1) + (a2 + a3);
      ts += __shfl_xor(ts, 16);
      ts += __shfl_xor(ts, 32);
      lsum[j] += ts;
      char* Pw = j ? Pw1 : Pw0;
      u32x2 wv;
      wv[0] = pkbf2(p[0],  p[1]);  wv[1] = pkbf2(p[2],  p[3]);
      *reinterpret_cast<u32x2*>(Pw + wr0) = wv;
      wv[0] = pkbf2(p[4],  p[5]);  wv[1] = pkbf2(p[6],  p[7]);
      *reinterpret_cast<u32x2*>(Pw + wr1) = wv;
      wv[0] = pkbf2(p[8],  p[9]);  wv[1] = pkbf2(p[10], p[11]);
      *reinterpret_cast<u32x2*>(Pw + wr2) = wv;
      wv[0] = pkbf2(p[12], p[13]); wv[1] = pkbf2(p[14], p[15]);
      *reinterpret_cast<u32x2*>(Pw + wr3) = wv;
    }
    __asm__ __volatile__("s_waitcnt lgkmcnt(0)" ::: "memory");
    bf16x8 pb[2][2];
    pb[0][0] = *reinterpret_cast<const bf16x8*>(Pw0 + rd0);
    pb[0][1] = *reinterpret_cast<const bf16x8*>(Pw0 + rd1);
    pb[1][0] = *reinterpret_cast<const bf16x8*>(Pw1 + rd0);
    pb[1][1] = *reinterpret_cast<const bf16x8*>(Pw1 + rd1);
    // ---- O^T += V^T * P^T both streams: shared va reads, 16 MFMA ----
#pragma unroll
    for (int dt = 0; dt < 4; ++dt) {
      const char* vp = Vt + (dt * 16 + r16) * 128;
      bf16x8 va0 = *reinterpret_cast<const bf16x8*>(vp + ((g * 16) ^ kswz));
      bf16x8 va1 = *reinterpret_cast<const bf16x8*>(vp + ((64 + g * 16) ^ kswz));
#pragma unroll
      for (int j = 0; j < 2; ++j) {
        oacc[j][dt] = __builtin_amdgcn_mfma_f32_16x16x32_bf16(va0, pb[j][0], oacc[j][dt], 0, 0, 0);
        oacc[j][dt] = __builtin_amdgcn_mfma_f32_16x16x32_bf16(va1, pb[j][1], oacc[j][dt], 0, 0, 0);
      }
    }
    __syncthreads();
  }

  // epilogue: stream j rows l0 + j*64; lane holds O^T[d=dt*16+g*4+r][q=r16]
#pragma unroll
  for (int j = 0; j < 2; ++j) {
    const float inv = 1.0f / lsum[j];
    const size_t orow = (size_t)(b * LL + l0 + j * 64 + r16) * 1024 + h * 64;
#pragma unroll
    for (int dt = 0; dt < 4; ++dt) {
      ushort4 pk;
      pk.x = f2bf(oacc[j][dt][0] * inv); pk.y = f2bf(oacc[j][dt][1] * inv);
      pk.z = f2bf(oacc[j][dt][2] * inv); pk.w = f2bf(oacc[j][dt][3] * inv);
      *reinterpret_cast<ushort4*>(ob + orow + dt * 16 + g * 4) = pk;
    }
  }
}

// ---------------- launch ----------------
extern "C" void kernel_launch(void* const* d_in, const int* in_sizes, int n_in,
                              void* d_out, int out_size, void* d_ws, size_t ws_size,
                              hipStream_t stream) {
  const float* x     = (const float*)d_in[0];
  const float* pe    = (const float*)d_in[1];
  const float* Wq    = (const float*)d_in[2];
  const float* Wkv   = (const float*)d_in[3];
  const float* Wproj = (const float*)d_in[4];
  const float* bproj = (const float*)d_in[5];
  const float* qs    = (const float*)d_in[6];
  const float* ks    = (const float*)d_in[7];
  float* out = (float*)d_out;

  char* ws = (char*)d_ws;
  unsigned short* xb     = (unsigned short*)(ws);                        //  8MB x bf16
  unsigned short* Wall   = (unsigned short*)(ws + 8u  * 1024 * 1024);    //  6MB [Wq;Wkv] bf16
  unsigned short* Wprojb = (unsigned short*)(ws + 14u * 1024 * 1024);    //  2MB
  unsigned short* qk     = (unsigned short*)(ws + 16u * 1024 * 1024);    // [4096][2048] 16MB (q|k)
  unsigned short* vT     = (unsigned short*)(ws + 32u * 1024 * 1024);    // [32*64][2048] 8MB
  unsigned short* ob     = (unsigned short*)(ws + 40u * 1024 * 1024);    // [4096][1024] 8MB

  k_cast_bf16<<<4194304 / 2048, 256, 0, stream>>>(x, xb, 4194304);
  k_cast_bf16<<<1048576 / 2048, 256, 0, stream>>>(Wq, Wall, 1048576);
  k_cast_bf16<<<2097152 / 2048, 256, 0, stream>>>(Wkv, Wall + 1048576, 2097152);
  k_cast_bf16<<<1048576 / 2048, 256, 0, stream>>>(Wproj, Wprojb, 1048576);

  k_gemm_qkv<<<dim3(32, 24), 256, 0, stream>>>(xb, Wall, qk, vT);

  k_norm_rope<<<BB * LL, 256, 0, stream>>>(qk, pe, qs, ks);
  k_flash<<<512, 256, 0, stream>>>(qk, vT, ob);

  k_gemm_proj<<<dim3(64, 8), 256, 0, stream>>>(ob, Wprojb, out, bproj);
}

// Round 10
// 223.554 us; speedup vs baseline: 1.0578x; 1.0578x over previous
//
#include <hip/hip_runtime.h>
#include <hip/hip_bf16.h>
#include <stdint.h>

// (B, L, QD, H, D) = (2, 2048, 1024, 16, 64)
#define BB 2
#define LL 2048
#define QDIM 1024
#define NH 16
#define HD 64

using bf16x8 = __attribute__((ext_vector_type(8))) __bf16;
using bf16x2 = __attribute__((ext_vector_type(2))) __bf16;
using f32x4  = __attribute__((ext_vector_type(4))) float;
using u16x8  = __attribute__((ext_vector_type(8))) unsigned short;
using u32x2  = __attribute__((ext_vector_type(2))) uint32_t;

__device__ __forceinline__ unsigned short f2bf(float f) {
  return __builtin_bit_cast(unsigned short, (__bf16)f);   // HW v_cvt (RNE)
}
__device__ __forceinline__ float bf2f(unsigned short h) {
  uint32_t u = ((uint32_t)h) << 16;
  return __builtin_bit_cast(float, u);
}
__device__ __forceinline__ uint32_t pkbf2(float a, float b) {
  bf16x2 v = { (__bf16)a, (__bf16)b };
  return __builtin_bit_cast(uint32_t, v);
}

__device__ __forceinline__ void gload_lds16(const void* g, void* l) {
  __builtin_amdgcn_global_load_lds((__attribute__((address_space(1))) void*)g,
                                   (__attribute__((address_space(3))) void*)l,
                                   16, 0, 0);
}

// ---------------- merged fp32 -> bf16 cast: x | Wq | Wkv | Wproj ----------------
// grid 4096: [0,2048) x, [2048,2560) Wq, [2560,3584) Wkv, [3584,4096) Wproj
__global__ __launch_bounds__(256) void k_cast_all(const float* __restrict__ x,
                                                  const float* __restrict__ wq,
                                                  const float* __restrict__ wkv,
                                                  const float* __restrict__ wp,
                                                  unsigned short* __restrict__ xb,
                                                  unsigned short* __restrict__ wall,
                                                  unsigned short* __restrict__ wpb) {
  const int blk = blockIdx.x;
  const float* src; unsigned short* dst; int base;
  if (blk < 2048)      { src = x;   dst = xb;             base = blk; }
  else if (blk < 2560) { src = wq;  dst = wall;           base = blk - 2048; }
  else if (blk < 3584) { src = wkv; dst = wall + 1048576; base = blk - 2560; }
  else                 { src = wp;  dst = wpb;            base = blk - 3584; }
  const int i = base * 2048 + threadIdx.x * 8;
  float4 a = *reinterpret_cast<const float4*>(src + i);
  float4 b = *reinterpret_cast<const float4*>(src + i + 4);
  u16x8 o;
  o[0] = f2bf(a.x); o[1] = f2bf(a.y); o[2] = f2bf(a.z); o[3] = f2bf(a.w);
  o[4] = f2bf(b.x); o[5] = f2bf(b.y); o[6] = f2bf(b.z); o[7] = f2bf(b.w);
  *reinterpret_cast<u16x8*>(dst + i) = o;
}

// ------- merged QKV GEMM + fused RMSNorm/RoPE + transposed-V, 128x128, BK=32, dbuf -------
// Wall rows: [0,1024)=Wq, [1024,2048)=Wk, [2048,3072)=Wv
// y<16 (q/k): norm+rope on f32 acc -> qk[row*2048+col] bf16 (q pre-scaled S2)
// y>=16 (v): LDS-transpose -> coalesced vT[(bh*64+d)*2048 + l]
__global__ __launch_bounds__(256) void k_gemm_qkv(const unsigned short* __restrict__ A,
                                                  const unsigned short* __restrict__ Bw,
                                                  unsigned short* __restrict__ qk,
                                                  unsigned short* __restrict__ vT,
                                                  const float* __restrict__ pe,
                                                  const float* __restrict__ qs,
                                                  const float* __restrict__ ks) {
  __shared__ char smem[32768];   // loop: As[2](16KB) | Bs[2](16KB); epilogue(v): 128x128 bf16 transpose
  const int t = threadIdx.x;
  const int lane = t & 63, w = t >> 6;
  const int wm = w >> 1, wn = w & 1;
  const int g = lane >> 4, r16 = lane & 15;
  const size_t am0 = (size_t)blockIdx.x * 128;
  const int bn0 = blockIdx.y * 128;
  const int K = 1024;
  const float S2 = 0.125f * 1.44269504f;   // 1/sqrt(64) * log2e

  f32x4 acc[4][4] = {};

  const int o0 = t * 16, row0 = o0 >> 6, cb0 = o0 & 63;
  const int o1 = 4096 + t * 16, row1 = o1 >> 6, cb1 = o1 & 63;

  char* As0 = smem;            // + cur*8192
  char* Bs0 = smem + 16384;

  gload_lds16(A  + (am0 + row0) * K + (cb0 >> 1), As0 + o0);
  gload_lds16(A  + (am0 + row1) * K + (cb1 >> 1), As0 + o1);
  gload_lds16(Bw + ((size_t)bn0 + row0) * K + (cb0 >> 1), Bs0 + o0);
  gload_lds16(Bw + ((size_t)bn0 + row1) * K + (cb1 >> 1), Bs0 + o1);
  __syncthreads();

  for (int kb = 0; kb < K; kb += 32) {
    const int cur = (kb >> 5) & 1;
    if (kb + 32 < K) {
      const int nxt = cur ^ 1;
      gload_lds16(A  + (am0 + row0) * K + kb + 32 + (cb0 >> 1), As0 + nxt * 8192 + o0);
      gload_lds16(A  + (am0 + row1) * K + kb + 32 + (cb1 >> 1), As0 + nxt * 8192 + o1);
      gload_lds16(Bw + ((size_t)bn0 + row0) * K + kb + 32 + (cb0 >> 1), Bs0 + nxt * 8192 + o0);
      gload_lds16(Bw + ((size_t)bn0 + row1) * K + kb + 32 + (cb1 >> 1), Bs0 + nxt * 8192 + o1);
    }
    bf16x8 af[4], bfr[4];
#pragma unroll
    for (int i = 0; i < 4; ++i)
      af[i] = *reinterpret_cast<const bf16x8*>(As0 + cur * 8192 + (wm * 64 + i * 16 + r16) * 64 + g * 16);
#pragma unroll
    for (int j = 0; j < 4; ++j)
      bfr[j] = *reinterpret_cast<const bf16x8*>(Bs0 + cur * 8192 + (wn * 64 + j * 16 + r16) * 64 + g * 16);
#pragma unroll
    for (int i = 0; i < 4; ++i)
#pragma unroll
      for (int j = 0; j < 4; ++j)
        acc[i][j] = __builtin_amdgcn_mfma_f32_16x16x32_bf16(af[i], bfr[j], acc[i][j], 0, 0, 0);
    __syncthreads();
  }

  if (bn0 < 2048) {
    // ---------------- q/k: fused RMSNorm + RoPE on f32 acc ----------------
    const bool isQ = (bn0 < 1024);
    float sc[4];
#pragma unroll
    for (int j = 0; j < 4; ++j) {
      const int d = j * 16 + r16;
      sc[j] = isQ ? qs[d] * S2 : ks[d];
    }
#pragma unroll
    for (int i = 0; i < 4; ++i) {
      const size_t rowb = am0 + wm * 64 + i * 16 + g * 4;
      float rr[4];
#pragma unroll
      for (int r = 0; r < 4; ++r) {
        float s = 0.f;
#pragma unroll
        for (int j = 0; j < 4; ++j) s += acc[i][j][r] * acc[i][j][r];
        s += __shfl_xor(s, 1); s += __shfl_xor(s, 2);
        s += __shfl_xor(s, 4); s += __shfl_xor(s, 8);
        rr[r] = rsqrtf(s * (1.0f / 64.0f) + 1e-6f);
      }
#pragma unroll
      for (int j = 0; j < 4; ++j) {
        const int d = j * 16 + r16;
        const int dp = d >> 1, odd = d & 1;
        const int col = bn0 + wn * 64 + d;
#pragma unroll
        for (int r = 0; r < 4; ++r) {
          const int l = (int)((rowb + r) & (LL - 1));
          float v = acc[i][j][r] * rr[r] * sc[j];
          float pr = __shfl_xor(v, 1);
          float xe = odd ? pr : v, xo = odd ? v : pr;
          const float2 pe2 = *reinterpret_cast<const float2*>(pe + ((size_t)l * 32 + dp) * 4 + odd * 2);
          qk[(rowb + r) * 2048 + col] = f2bf(pe2.x * xe + pe2.y * xo);
        }
      }
    }
  } else {
    // ---------------- v: LDS transpose -> coalesced vT stores ----------------
    unsigned short* Tr = (unsigned short*)smem;   // [c:128][row:128] bf16, swizzled
#pragma unroll
    for (int i = 0; i < 4; ++i)
#pragma unroll
      for (int j = 0; j < 4; ++j) {
        const int c = wn * 64 + j * 16 + r16;
        const int rw = wm * 64 + i * 16 + g * 4;
        const int byte = c * 256 + ((rw * 2) ^ ((c & 7) << 4));
        u32x2 pk;
        pk[0] = pkbf2(acc[i][j][0], acc[i][j][1]);
        pk[1] = pkbf2(acc[i][j][2], acc[i][j][3]);
        *reinterpret_cast<u32x2*>((char*)Tr + byte) = pk;
      }
    __syncthreads();
    const int b = (int)(am0 >> 11);
    const int lbase = (int)(am0 & (LL - 1));
#pragma unroll
    for (int p = 0; p < 8; ++p) {
      const int c = p * 16 + (t >> 4);    // 0..127
      const int ch = t & 15;
      const int byte = c * 256 + ((ch * 16) ^ ((c & 7) << 4));
      u16x8 val = *reinterpret_cast<const u16x8*>((char*)Tr + byte);
      const int e = bn0 + c - 2048, h = e >> 6, d = e & 63;
      *reinterpret_cast<u16x8*>(vT + ((size_t)(b * 16 + h) * 64 + d) * 2048 + lbase + ch * 8) = val;
    }
  }
}

// ------- proj GEMM: out = ob * Wproj^T + bias, 64x128 tile, LDS double-buffered -------
__global__ __launch_bounds__(256) void k_gemm_proj(const unsigned short* __restrict__ A,
                                                   const unsigned short* __restrict__ Bw,
                                                   float* __restrict__ Cf,
                                                   const float* __restrict__ bias) {
  __shared__ unsigned short As[2][64 * 32];
  __shared__ unsigned short Bs[2][128 * 32];
  const int t = threadIdx.x;
  const int lane = t & 63, w = t >> 6;
  const int wm = w >> 1, wn = w & 1;
  const int g = lane >> 4, r16 = lane & 15;
  const size_t am0 = (size_t)blockIdx.x * 64;
  const size_t bn0 = (size_t)blockIdx.y * 128;
  const int K = 1024;

  f32x4 acc[2][4] = {};

  const int oa = t * 16, rowa = oa >> 6, cba = oa & 63;
  const int ob0 = t * 16, rowb0 = ob0 >> 6, cbb0 = ob0 & 63;
  const int ob1 = 4096 + t * 16, rowb1 = ob1 >> 6, cbb1 = ob1 & 63;

  gload_lds16(A  + (am0 + rowa)  * K + (cba  >> 1), (char*)&As[0][0] + oa);
  gload_lds16(Bw + (bn0 + rowb0) * K + (cbb0 >> 1), (char*)&Bs[0][0] + ob0);
  gload_lds16(Bw + (bn0 + rowb1) * K + (cbb1 >> 1), (char*)&Bs[0][0] + ob1);
  __syncthreads();

  for (int kb = 0; kb < K; kb += 32) {
    const int cur = (kb >> 5) & 1;
    if (kb + 32 < K) {
      const int nxt = cur ^ 1;
      gload_lds16(A  + (am0 + rowa)  * K + kb + 32 + (cba  >> 1), (char*)&As[nxt][0] + oa);
      gload_lds16(Bw + (bn0 + rowb0) * K + kb + 32 + (cbb0 >> 1), (char*)&Bs[nxt][0] + ob0);
      gload_lds16(Bw + (bn0 + rowb1) * K + kb + 32 + (cbb1 >> 1), (char*)&Bs[nxt][0] + ob1);
    }
    bf16x8 af[2], bfr[4];
#pragma unroll
    for (int i = 0; i < 2; ++i)
      af[i] = *reinterpret_cast<const bf16x8*>((const char*)&As[cur][0] + (wm * 32 + i * 16 + r16) * 64 + g * 16);
#pragma unroll
    for (int j = 0; j < 4; ++j)
      bfr[j] = *reinterpret_cast<const bf16x8*>((const char*)&Bs[cur][0] + (wn * 64 + j * 16 + r16) * 64 + g * 16);
#pragma unroll
    for (int i = 0; i < 2; ++i)
#pragma unroll
      for (int j = 0; j < 4; ++j)
        acc[i][j] = __builtin_amdgcn_mfma_f32_16x16x32_bf16(af[i], bfr[j], acc[i][j], 0, 0, 0);
    __syncthreads();
  }

#pragma unroll
  for (int i = 0; i < 2; ++i)
#pragma unroll
    for (int j = 0; j < 4; ++j) {
      size_t row = am0 + wm * 32 + i * 16 + g * 4;
      int col = (int)bn0 + wn * 64 + j * 16 + r16;
#pragma unroll
      for (int r = 0; r < 4; ++r) Cf[(row + r) * 1024 + col] = acc[i][j][r] + bias[col];
    }
}

// ---- flash attention: swapped operands, 2 q-streams/wave, LDS K/V 2-phase, exp2/defer-max ----
__global__ __launch_bounds__(256, 2) void k_flash(const unsigned short* __restrict__ qkbuf,
                                                  const unsigned short* __restrict__ vT,
                                                  unsigned short* __restrict__ ob) {
  __shared__ unsigned short Ktile[2][64 * 64];
  __shared__ unsigned short Vtile[2][64 * 64];
  __shared__ unsigned short Plds[4][2][16 * 64];
  const int t = threadIdx.x, w = t >> 6, lane = t & 63;
  const int g = lane >> 4, r16 = lane & 15;
  const int id = blockIdx.x;                        // 0..511
  const int bh = (id & 7) + (((id >> 3) & 3) << 3);
  const int lt = id >> 5;
  const int b = bh >> 4, h = bh & 15;
  const int l0 = lt * 128 + w * 16;
  const size_t qkb = (size_t)b * LL * 2048;
  const unsigned short* Qp = qkbuf + qkb + (size_t)(l0 + r16) * 2048 + h * 64;
  const unsigned short* Kbase = qkbuf + qkb + 1024 + h * 64;
  const unsigned short* Vbase = vT + (size_t)bh * 64 * 2048;

  bf16x8 qf[2][2];
  qf[0][0] = *reinterpret_cast<const bf16x8*>(Qp + g * 8);
  qf[0][1] = *reinterpret_cast<const bf16x8*>(Qp + 32 + g * 8);
  qf[1][0] = *reinterpret_cast<const bf16x8*>(Qp + (size_t)64 * 2048 + g * 8);
  qf[1][1] = *reinterpret_cast<const bf16x8*>(Qp + (size_t)64 * 2048 + 32 + g * 8);

  f32x4 oacc[2][4] = {};
  float m[2] = {-1e30f, -1e30f}, lsum[2] = {0.f, 0.f};

  char* Pw0 = (char*)&Plds[w][0][0];
  char* Pw1 = (char*)&Plds[w][1][0];
  const int pswz = (r16 & 7) << 4;
  const int prow = r16 * 128;
  const int wr0 = prow + ((0 * 32 + g * 8) ^ pswz);
  const int wr1 = prow + ((1 * 32 + g * 8) ^ pswz);
  const int wr2 = prow + ((2 * 32 + g * 8) ^ pswz);
  const int wr3 = prow + ((3 * 32 + g * 8) ^ pswz);
  const int rd0 = prow + ((g * 16) ^ pswz);
  const int rd1 = prow + ((64 + g * 16) ^ pswz);

  const int so0 = t * 16, sr0 = so0 >> 7, sl0 = (so0 & 127) ^ ((sr0 & 7) << 4);
  const int so1 = 4096 + t * 16, sr1 = so1 >> 7, sl1 = (so1 & 127) ^ ((sr1 & 7) << 4);

  gload_lds16(Kbase + (size_t)sr0 * 2048 + (sl0 >> 1), (char*)&Ktile[0][0] + so0);
  gload_lds16(Kbase + (size_t)sr1 * 2048 + (sl1 >> 1), (char*)&Ktile[0][0] + so1);
  gload_lds16(Vbase + (size_t)sr0 * 2048 + (sl0 >> 1), (char*)&Vtile[0][0] + so0);
  gload_lds16(Vbase + (size_t)sr1 * 2048 + (sl1 >> 1), (char*)&Vtile[0][0] + so1);
  __syncthreads();

  const int kswz = (r16 & 7) << 4;

  for (int kt = 0; kt < LL; kt += 64) {
    const int cur = (kt >> 6) & 1;
    if (kt + 64 < LL) {
      const int nxt = cur ^ 1;
      gload_lds16(Kbase + (size_t)(kt + 64 + sr0) * 2048 + (sl0 >> 1), (char*)&Ktile[nxt][0] + so0);
      gload_lds16(Kbase + (size_t)(kt + 64 + sr1) * 2048 + (sl1 >> 1), (char*)&Ktile[nxt][0] + so1);
      gload_lds16(Vbase + (size_t)sr0 * 2048 + kt + 64 + (sl0 >> 1), (char*)&Vtile[nxt][0] + so0);
      gload_lds16(Vbase + (size_t)sr1 * 2048 + kt + 64 + (sl1 >> 1), (char*)&Vtile[nxt][0] + so1);
    }
    const char* Kt = (const char*)&Ktile[cur][0];
    const char* Vt = (const char*)&Vtile[cur][0];

    f32x4 s[2][4];
#pragma unroll
    for (int kb = 0; kb < 4; ++kb) {
      const char* kp = Kt + (kb * 16 + r16) * 128;
      bf16x8 ka0 = *reinterpret_cast<const bf16x8*>(kp + ((g * 16) ^ kswz));
      bf16x8 ka1 = *reinterpret_cast<const bf16x8*>(kp + ((64 + g * 16) ^ kswz));
#pragma unroll
      for (int j = 0; j < 2; ++j) {
        f32x4 z = {};
        z = __builtin_amdgcn_mfma_f32_16x16x32_bf16(ka0, qf[j][0], z, 0, 0, 0);
        z = __builtin_amdgcn_mfma_f32_16x16x32_bf16(ka1, qf[j][1], z, 0, 0, 0);
        s[j][kb] = z;
      }
    }
#pragma unroll
    for (int j = 0; j < 2; ++j) {
      float p[16];
#pragma unroll
      for (int kb = 0; kb < 4; ++kb)
#pragma unroll
        for (int r = 0; r < 4; ++r) p[kb * 4 + r] = s[j][kb][r];
      float t0 = fmaxf(fmaxf(p[0], p[1]), p[2]);
      float t1 = fmaxf(fmaxf(p[3], p[4]), p[5]);
      float t2 = fmaxf(fmaxf(p[6], p[7]), p[8]);
      float t3 = fmaxf(fmaxf(p[9], p[10]), p[11]);
      float t4 = fmaxf(fmaxf(p[12], p[13]), p[14]);
      float tm = fmaxf(fmaxf(fmaxf(t0, t1), t2), fmaxf(fmaxf(t3, t4), p[15]));
      tm = fmaxf(tm, __shfl_xor(tm, 16));
      tm = fmaxf(tm, __shfl_xor(tm, 32));
      if (!__all(tm <= m[j] + 11.0f)) {
        float nm = fmaxf(m[j], tm);
        float alpha = __builtin_exp2f(m[j] - nm);
        lsum[j] *= alpha;
#pragma unroll
        for (int dt = 0; dt < 4; ++dt) oacc[j][dt] *= alpha;
        m[j] = nm;
      }
#pragma unroll
      for (int i = 0; i < 16; ++i) p[i] = __builtin_exp2f(p[i] - m[j]);
      float a0 = (p[0] + p[1]) + (p[2] + p[3]);
      float a1 = (p[4] + p[5]) + (p[6] + p[7]);
      float a2 = (p[8] + p[9]) + (p[10] + p[11]);
      float a3 = (p[12] + p[13]) + (p[14] + p[15]);
      float ts = (a0 + a1) + (a2 + a3);
      ts += __shfl_xor(ts, 16);
      ts += __shfl_xor(ts, 32);
      lsum[j] += ts;
      char* Pw = j ? Pw1 : Pw0;
      u32x2 wv;
      wv[0] = pkbf2(p[0],  p[1]);  wv[1] = pkbf2(p[2],  p[3]);
      *reinterpret_cast<u32x2*>(Pw + wr0) = wv;
      wv[0] = pkbf2(p[4],  p[5]);  wv[1] = pkbf2(p[6],  p[7]);
      *reinterpret_cast<u32x2*>(Pw + wr1) = wv;
      wv[0] = pkbf2(p[8],  p[9]);  wv[1] = pkbf2(p[10], p[11]);
      *reinterpret_cast<u32x2*>(Pw + wr2) = wv;
      wv[0] = pkbf2(p[12], p[13]); wv[1] = pkbf2(p[14], p[15]);
      *reinterpret_cast<u32x2*>(Pw + wr3) = wv;
    }
    __asm__ __volatile__("s_waitcnt lgkmcnt(0)" ::: "memory");
    bf16x8 pb[2][2];
    pb[0][0] = *reinterpret_cast<const bf16x8*>(Pw0 + rd0);
    pb[0][1] = *reinterpret_cast<const bf16x8*>(Pw0 + rd1);
    pb[1][0] = *reinterpret_cast<const bf16x8*>(Pw1 + rd0);
    pb[1][1] = *reinterpret_cast<const bf16x8*>(Pw1 + rd1);
#pragma unroll
    for (int dt = 0; dt < 4; ++dt) {
      const char* vp = Vt + (dt * 16 + r16) * 128;
      bf16x8 va0 = *reinterpret_cast<const bf16x8*>(vp + ((g * 16) ^ kswz));
      bf16x8 va1 = *reinterpret_cast<const bf16x8*>(vp + ((64 + g * 16) ^ kswz));
#pragma unroll
      for (int j = 0; j < 2; ++j) {
        oacc[j][dt] = __builtin_amdgcn_mfma_f32_16x16x32_bf16(va0, pb[j][0], oacc[j][dt], 0, 0, 0);
        oacc[j][dt] = __builtin_amdgcn_mfma_f32_16x16x32_bf16(va1, pb[j][1], oacc[j][dt], 0, 0, 0);
      }
    }
    __syncthreads();
  }

#pragma unroll
  for (int j = 0; j < 2; ++j) {
    const float inv = 1.0f / lsum[j];
    const size_t orow = (size_t)(b * LL + l0 + j * 64 + r16) * 1024 + h * 64;
#pragma unroll
    for (int dt = 0; dt < 4; ++dt) {
      ushort4 pk;
      pk.x = f2bf(oacc[j][dt][0] * inv); pk.y = f2bf(oacc[j][dt][1] * inv);
      pk.z = f2bf(oacc[j][dt][2] * inv); pk.w = f2bf(oacc[j][dt][3] * inv);
      *reinterpret_cast<ushort4*>(ob + orow + dt * 16 + g * 4) = pk;
    }
  }
}

// ---------------- launch ----------------
extern "C" void kernel_launch(void* const* d_in, const int* in_sizes, int n_in,
                              void* d_out, int out_size, void* d_ws, size_t ws_size,
                              hipStream_t stream) {
  const float* x     = (const float*)d_in[0];
  const float* pe    = (const float*)d_in[1];
  const float* Wq    = (const float*)d_in[2];
  const float* Wkv   = (const float*)d_in[3];
  const float* Wproj = (const float*)d_in[4];
  const float* bproj = (const float*)d_in[5];
  const float* qs    = (const float*)d_in[6];
  const float* ks    = (const float*)d_in[7];
  float* out = (float*)d_out;

  char* ws = (char*)d_ws;
  unsigned short* xb     = (unsigned short*)(ws);                        //  8MB x bf16
  unsigned short* Wall   = (unsigned short*)(ws + 8u  * 1024 * 1024);    //  6MB [Wq;Wkv]
  unsigned short* Wprojb = (unsigned short*)(ws + 14u * 1024 * 1024);    //  2MB
  unsigned short* qk     = (unsigned short*)(ws + 16u * 1024 * 1024);    // [4096][2048] 16MB
  unsigned short* vT     = (unsigned short*)(ws + 32u * 1024 * 1024);    // [32*64][2048] 8MB
  unsigned short* ob     = (unsigned short*)(ws + 40u * 1024 * 1024);    // [4096][1024] 8MB

  k_cast_all<<<4096, 256, 0, stream>>>(x, Wq, Wkv, Wproj, xb, Wall, Wprojb);
  k_gemm_qkv<<<dim3(32, 24), 256, 0, stream>>>(xb, Wall, qk, vT, pe, qs, ks);
  k_flash<<<512, 256, 0, stream>>>(qk, vT, ob);
  k_gemm_proj<<<dim3(64, 8), 256, 0, stream>>>(ob, Wprojb, out, bproj);
}

// Round 11
// 218.372 us; speedup vs baseline: 1.0829x; 1.0237x over previous
//
#include <hip/hip_runtime.h>
#include <hip/hip_bf16.h>
#include <stdint.h>

// (B, L, QD, H, D) = (2, 2048, 1024, 16, 64)
#define BB 2
#define LL 2048
#define QDIM 1024
#define NH 16
#define HD 64

using bf16x8 = __attribute__((ext_vector_type(8))) __bf16;
using bf16x4 = __attribute__((ext_vector_type(4))) __bf16;
using bf16x2 = __attribute__((ext_vector_type(2))) __bf16;
using f32x4  = __attribute__((ext_vector_type(4))) float;
using u16x8  = __attribute__((ext_vector_type(8))) unsigned short;
using u32x2  = __attribute__((ext_vector_type(2))) uint32_t;
using s16x4  = __attribute__((ext_vector_type(4))) short;

__device__ __forceinline__ unsigned short f2bf(float f) {
  return __builtin_bit_cast(unsigned short, (__bf16)f);   // HW v_cvt (RNE)
}
__device__ __forceinline__ float bf2f(unsigned short h) {
  uint32_t u = ((uint32_t)h) << 16;
  return __builtin_bit_cast(float, u);
}
__device__ __forceinline__ uint32_t pkbf2(float a, float b) {
  bf16x2 v = { (__bf16)a, (__bf16)b };
  return __builtin_bit_cast(uint32_t, v);
}

// K=16 bf16 MFMA: B-operand layout (col=lane&15, k=(lane>>4)*4+j) matches the
// swapped-QK^T C-layout exactly -> P stays in registers (no LDS round-trip).
__device__ __forceinline__ f32x4 mfma16(u32x2 a, u32x2 b, f32x4 c) {
#if __has_builtin(__builtin_amdgcn_mfma_f32_16x16x16_bf16)
  return __builtin_amdgcn_mfma_f32_16x16x16_bf16(__builtin_bit_cast(bf16x4, a),
                                                 __builtin_bit_cast(bf16x4, b), c, 0, 0, 0);
#elif __has_builtin(__builtin_amdgcn_mfma_f32_16x16x16bf16_1k)
  return __builtin_amdgcn_mfma_f32_16x16x16bf16_1k(__builtin_bit_cast(s16x4, a),
                                                   __builtin_bit_cast(s16x4, b), c, 0, 0, 0);
#else
  asm("v_mfma_f32_16x16x16_bf16 %0, %1, %2, %0" : "+v"(c) : "v"(a), "v"(b));
  return c;
#endif
}

__device__ __forceinline__ void gload_lds16(const void* g, void* l) {
  __builtin_amdgcn_global_load_lds((__attribute__((address_space(1))) void*)g,
                                   (__attribute__((address_space(3))) void*)l,
                                   16, 0, 0);
}

// ---------------- merged fp32 -> bf16 cast: x | Wq | Wkv | Wproj ----------------
__global__ __launch_bounds__(256) void k_cast_all(const float* __restrict__ x,
                                                  const float* __restrict__ wq,
                                                  const float* __restrict__ wkv,
                                                  const float* __restrict__ wp,
                                                  unsigned short* __restrict__ xb,
                                                  unsigned short* __restrict__ wall,
                                                  unsigned short* __restrict__ wpb) {
  const int blk = blockIdx.x;
  const float* src; unsigned short* dst; int base;
  if (blk < 2048)      { src = x;   dst = xb;             base = blk; }
  else if (blk < 2560) { src = wq;  dst = wall;           base = blk - 2048; }
  else if (blk < 3584) { src = wkv; dst = wall + 1048576; base = blk - 2560; }
  else                 { src = wp;  dst = wpb;            base = blk - 3584; }
  const int i = base * 2048 + threadIdx.x * 8;
  float4 a = *reinterpret_cast<const float4*>(src + i);
  float4 b = *reinterpret_cast<const float4*>(src + i + 4);
  u16x8 o;
  o[0] = f2bf(a.x); o[1] = f2bf(a.y); o[2] = f2bf(a.z); o[3] = f2bf(a.w);
  o[4] = f2bf(b.x); o[5] = f2bf(b.y); o[6] = f2bf(b.z); o[7] = f2bf(b.w);
  *reinterpret_cast<u16x8*>(dst + i) = o;
}

// ------- merged QKV GEMM + fused RMSNorm/RoPE + transposed-V, 128x128, BK=32, dbuf -------
__global__ __launch_bounds__(256) void k_gemm_qkv(const unsigned short* __restrict__ A,
                                                  const unsigned short* __restrict__ Bw,
                                                  unsigned short* __restrict__ qk,
                                                  unsigned short* __restrict__ vT,
                                                  const float* __restrict__ pe,
                                                  const float* __restrict__ qs,
                                                  const float* __restrict__ ks) {
  __shared__ char smem[32768];
  const int t = threadIdx.x;
  const int lane = t & 63, w = t >> 6;
  const int wm = w >> 1, wn = w & 1;
  const int g = lane >> 4, r16 = lane & 15;
  const size_t am0 = (size_t)blockIdx.x * 128;
  const int bn0 = blockIdx.y * 128;
  const int K = 1024;
  const float S2 = 0.125f * 1.44269504f;

  f32x4 acc[4][4] = {};

  const int o0 = t * 16, row0 = o0 >> 6, cb0 = o0 & 63;
  const int o1 = 4096 + t * 16, row1 = o1 >> 6, cb1 = o1 & 63;

  char* As0 = smem;
  char* Bs0 = smem + 16384;

  gload_lds16(A  + (am0 + row0) * K + (cb0 >> 1), As0 + o0);
  gload_lds16(A  + (am0 + row1) * K + (cb1 >> 1), As0 + o1);
  gload_lds16(Bw + ((size_t)bn0 + row0) * K + (cb0 >> 1), Bs0 + o0);
  gload_lds16(Bw + ((size_t)bn0 + row1) * K + (cb1 >> 1), Bs0 + o1);
  __syncthreads();

  for (int kb = 0; kb < K; kb += 32) {
    const int cur = (kb >> 5) & 1;
    if (kb + 32 < K) {
      const int nxt = cur ^ 1;
      gload_lds16(A  + (am0 + row0) * K + kb + 32 + (cb0 >> 1), As0 + nxt * 8192 + o0);
      gload_lds16(A  + (am0 + row1) * K + kb + 32 + (cb1 >> 1), As0 + nxt * 8192 + o1);
      gload_lds16(Bw + ((size_t)bn0 + row0) * K + kb + 32 + (cb0 >> 1), Bs0 + nxt * 8192 + o0);
      gload_lds16(Bw + ((size_t)bn0 + row1) * K + kb + 32 + (cb1 >> 1), Bs0 + nxt * 8192 + o1);
    }
    bf16x8 af[4], bfr[4];
#pragma unroll
    for (int i = 0; i < 4; ++i)
      af[i] = *reinterpret_cast<const bf16x8*>(As0 + cur * 8192 + (wm * 64 + i * 16 + r16) * 64 + g * 16);
#pragma unroll
    for (int j = 0; j < 4; ++j)
      bfr[j] = *reinterpret_cast<const bf16x8*>(Bs0 + cur * 8192 + (wn * 64 + j * 16 + r16) * 64 + g * 16);
#pragma unroll
    for (int i = 0; i < 4; ++i)
#pragma unroll
      for (int j = 0; j < 4; ++j)
        acc[i][j] = __builtin_amdgcn_mfma_f32_16x16x32_bf16(af[i], bfr[j], acc[i][j], 0, 0, 0);
    __syncthreads();
  }

  if (bn0 < 2048) {
    const bool isQ = (bn0 < 1024);
    float sc[4];
#pragma unroll
    for (int j = 0; j < 4; ++j) {
      const int d = j * 16 + r16;
      sc[j] = isQ ? qs[d] * S2 : ks[d];
    }
#pragma unroll
    for (int i = 0; i < 4; ++i) {
      const size_t rowb = am0 + wm * 64 + i * 16 + g * 4;
      float rr[4];
#pragma unroll
      for (int r = 0; r < 4; ++r) {
        float s = 0.f;
#pragma unroll
        for (int j = 0; j < 4; ++j) s += acc[i][j][r] * acc[i][j][r];
        s += __shfl_xor(s, 1); s += __shfl_xor(s, 2);
        s += __shfl_xor(s, 4); s += __shfl_xor(s, 8);
        rr[r] = rsqrtf(s * (1.0f / 64.0f) + 1e-6f);
      }
#pragma unroll
      for (int j = 0; j < 4; ++j) {
        const int d = j * 16 + r16;
        const int dp = d >> 1, odd = d & 1;
        const int col = bn0 + wn * 64 + d;
#pragma unroll
        for (int r = 0; r < 4; ++r) {
          const int l = (int)((rowb + r) & (LL - 1));
          float v = acc[i][j][r] * rr[r] * sc[j];
          float pr = __shfl_xor(v, 1);
          float xe = odd ? pr : v, xo = odd ? v : pr;
          const float2 pe2 = *reinterpret_cast<const float2*>(pe + ((size_t)l * 32 + dp) * 4 + odd * 2);
          qk[(rowb + r) * 2048 + col] = f2bf(pe2.x * xe + pe2.y * xo);
        }
      }
    }
  } else {
    unsigned short* Tr = (unsigned short*)smem;
#pragma unroll
    for (int i = 0; i < 4; ++i)
#pragma unroll
      for (int j = 0; j < 4; ++j) {
        const int c = wn * 64 + j * 16 + r16;
        const int rw = wm * 64 + i * 16 + g * 4;
        const int byte = c * 256 + ((rw * 2) ^ ((c & 7) << 4));
        u32x2 pk;
        pk[0] = pkbf2(acc[i][j][0], acc[i][j][1]);
        pk[1] = pkbf2(acc[i][j][2], acc[i][j][3]);
        *reinterpret_cast<u32x2*>((char*)Tr + byte) = pk;
      }
    __syncthreads();
    const int b = (int)(am0 >> 11);
    const int lbase = (int)(am0 & (LL - 1));
#pragma unroll
    for (int p = 0; p < 8; ++p) {
      const int c = p * 16 + (t >> 4);
      const int ch = t & 15;
      const int byte = c * 256 + ((ch * 16) ^ ((c & 7) << 4));
      u16x8 val = *reinterpret_cast<const u16x8*>((char*)Tr + byte);
      const int e = bn0 + c - 2048, h = e >> 6, d = e & 63;
      *reinterpret_cast<u16x8*>(vT + ((size_t)(b * 16 + h) * 64 + d) * 2048 + lbase + ch * 8) = val;
    }
  }
}

// ------- proj GEMM: out = ob * Wproj^T + bias, 64x128 tile, LDS double-buffered -------
__global__ __launch_bounds__(256) void k_gemm_proj(const unsigned short* __restrict__ A,
                                                   const unsigned short* __restrict__ Bw,
                                                   float* __restrict__ Cf,
                                                   const float* __restrict__ bias) {
  __shared__ unsigned short As[2][64 * 32];
  __shared__ unsigned short Bs[2][128 * 32];
  const int t = threadIdx.x;
  const int lane = t & 63, w = t >> 6;
  const int wm = w >> 1, wn = w & 1;
  const int g = lane >> 4, r16 = lane & 15;
  const size_t am0 = (size_t)blockIdx.x * 64;
  const size_t bn0 = (size_t)blockIdx.y * 128;
  const int K = 1024;

  f32x4 acc[2][4] = {};

  const int oa = t * 16, rowa = oa >> 6, cba = oa & 63;
  const int ob0 = t * 16, rowb0 = ob0 >> 6, cbb0 = ob0 & 63;
  const int ob1 = 4096 + t * 16, rowb1 = ob1 >> 6, cbb1 = ob1 & 63;

  gload_lds16(A  + (am0 + rowa)  * K + (cba  >> 1), (char*)&As[0][0] + oa);
  gload_lds16(Bw + (bn0 + rowb0) * K + (cbb0 >> 1), (char*)&Bs[0][0] + ob0);
  gload_lds16(Bw + (bn0 + rowb1) * K + (cbb1 >> 1), (char*)&Bs[0][0] + ob1);
  __syncthreads();

  for (int kb = 0; kb < K; kb += 32) {
    const int cur = (kb >> 5) & 1;
    if (kb + 32 < K) {
      const int nxt = cur ^ 1;
      gload_lds16(A  + (am0 + rowa)  * K + kb + 32 + (cba  >> 1), (char*)&As[nxt][0] + oa);
      gload_lds16(Bw + (bn0 + rowb0) * K + kb + 32 + (cbb0 >> 1), (char*)&Bs[nxt][0] + ob0);
      gload_lds16(Bw + (bn0 + rowb1) * K + kb + 32 + (cbb1 >> 1), (char*)&Bs[nxt][0] + ob1);
    }
    bf16x8 af[2], bfr[4];
#pragma unroll
    for (int i = 0; i < 2; ++i)
      af[i] = *reinterpret_cast<const bf16x8*>((const char*)&As[cur][0] + (wm * 32 + i * 16 + r16) * 64 + g * 16);
#pragma unroll
    for (int j = 0; j < 4; ++j)
      bfr[j] = *reinterpret_cast<const bf16x8*>((const char*)&Bs[cur][0] + (wn * 64 + j * 16 + r16) * 64 + g * 16);
#pragma unroll
    for (int i = 0; i < 2; ++i)
#pragma unroll
      for (int j = 0; j < 4; ++j)
        acc[i][j] = __builtin_amdgcn_mfma_f32_16x16x32_bf16(af[i], bfr[j], acc[i][j], 0, 0, 0);
    __syncthreads();
  }

#pragma unroll
  for (int i = 0; i < 2; ++i)
#pragma unroll
    for (int j = 0; j < 4; ++j) {
      size_t row = am0 + wm * 32 + i * 16 + g * 4;
      int col = (int)bn0 + wn * 64 + j * 16 + r16;
#pragma unroll
      for (int r = 0; r < 4; ++r) Cf[(row + r) * 1024 + col] = acc[i][j][r] + bias[col];
    }
}

// ---- flash attention: swapped operands, 2 q-streams/wave, LDS K/V 2-phase,
//      exp2/defer-max, PV via K=16 MFMA with P fully in registers ----
__global__ __launch_bounds__(256, 2) void k_flash(const unsigned short* __restrict__ qkbuf,
                                                  const unsigned short* __restrict__ vT,
                                                  unsigned short* __restrict__ ob) {
  __shared__ unsigned short Ktile[2][64 * 64];   // 16KB dbuf K
  __shared__ unsigned short Vtile[2][64 * 64];   // 16KB dbuf V^T
  const int t = threadIdx.x, w = t >> 6, lane = t & 63;
  const int g = lane >> 4, r16 = lane & 15;
  const int id = blockIdx.x;                        // 0..511
  const int bh = (id & 7) + (((id >> 3) & 3) << 3); // all 16 l-tiles of a bh on one XCD
  const int lt = id >> 5;
  const int b = bh >> 4, h = bh & 15;
  const int l0 = lt * 128 + w * 16;
  const size_t qkb = (size_t)b * LL * 2048;
  const unsigned short* Qp = qkbuf + qkb + (size_t)(l0 + r16) * 2048 + h * 64;
  const unsigned short* Kbase = qkbuf + qkb + 1024 + h * 64;
  const unsigned short* Vbase = vT + (size_t)bh * 64 * 2048;

  bf16x8 qf[2][2];
  qf[0][0] = *reinterpret_cast<const bf16x8*>(Qp + g * 8);
  qf[0][1] = *reinterpret_cast<const bf16x8*>(Qp + 32 + g * 8);
  qf[1][0] = *reinterpret_cast<const bf16x8*>(Qp + (size_t)64 * 2048 + g * 8);
  qf[1][1] = *reinterpret_cast<const bf16x8*>(Qp + (size_t)64 * 2048 + 32 + g * 8);

  f32x4 oacc[2][4] = {};
  float m[2] = {-1e30f, -1e30f}, lsum[2] = {0.f, 0.f};

  const int so0 = t * 16, sr0 = so0 >> 7, sl0 = (so0 & 127) ^ ((sr0 & 7) << 4);
  const int so1 = 4096 + t * 16, sr1 = so1 >> 7, sl1 = (so1 & 127) ^ ((sr1 & 7) << 4);

  gload_lds16(Kbase + (size_t)sr0 * 2048 + (sl0 >> 1), (char*)&Ktile[0][0] + so0);
  gload_lds16(Kbase + (size_t)sr1 * 2048 + (sl1 >> 1), (char*)&Ktile[0][0] + so1);
  gload_lds16(Vbase + (size_t)sr0 * 2048 + (sl0 >> 1), (char*)&Vtile[0][0] + so0);
  gload_lds16(Vbase + (size_t)sr1 * 2048 + (sl1 >> 1), (char*)&Vtile[0][0] + so1);
  __syncthreads();

  const int kswz = (r16 & 7) << 4;

  for (int kt = 0; kt < LL; kt += 64) {
    const int cur = (kt >> 6) & 1;
    if (kt + 64 < LL) {
      const int nxt = cur ^ 1;
      gload_lds16(Kbase + (size_t)(kt + 64 + sr0) * 2048 + (sl0 >> 1), (char*)&Ktile[nxt][0] + so0);
      gload_lds16(Kbase + (size_t)(kt + 64 + sr1) * 2048 + (sl1 >> 1), (char*)&Ktile[nxt][0] + so1);
      gload_lds16(Vbase + (size_t)sr0 * 2048 + kt + 64 + (sl0 >> 1), (char*)&Vtile[nxt][0] + so0);
      gload_lds16(Vbase + (size_t)sr1 * 2048 + kt + 64 + (sl1 >> 1), (char*)&Vtile[nxt][0] + so1);
    }
    const char* Kt = (const char*)&Ktile[cur][0];
    const char* Vt = (const char*)&Vtile[cur][0];

    // ---- QK^T both streams: shared ka reads, 16 MFMA ----
    f32x4 s[2][4];
    __builtin_amdgcn_s_setprio(1);
#pragma unroll
    for (int kb = 0; kb < 4; ++kb) {
      const char* kp = Kt + (kb * 16 + r16) * 128;
      bf16x8 ka0 = *reinterpret_cast<const bf16x8*>(kp + ((g * 16) ^ kswz));
      bf16x8 ka1 = *reinterpret_cast<const bf16x8*>(kp + ((64 + g * 16) ^ kswz));
#pragma unroll
      for (int j = 0; j < 2; ++j) {
        f32x4 z = {};
        z = __builtin_amdgcn_mfma_f32_16x16x32_bf16(ka0, qf[j][0], z, 0, 0, 0);
        z = __builtin_amdgcn_mfma_f32_16x16x32_bf16(ka1, qf[j][1], z, 0, 0, 0);
        s[j][kb] = z;
      }
    }
    __builtin_amdgcn_s_setprio(0);

    // ---- online softmax per stream (exp2 domain, defer-max); P packed to regs ----
    u32x2 pbv[2][4];
#pragma unroll
    for (int j = 0; j < 2; ++j) {
      float p[16];
#pragma unroll
      for (int kb = 0; kb < 4; ++kb)
#pragma unroll
        for (int r = 0; r < 4; ++r) p[kb * 4 + r] = s[j][kb][r];
      float t0 = fmaxf(fmaxf(p[0], p[1]), p[2]);
      float t1 = fmaxf(fmaxf(p[3], p[4]), p[5]);
      float t2 = fmaxf(fmaxf(p[6], p[7]), p[8]);
      float t3 = fmaxf(fmaxf(p[9], p[10]), p[11]);
      float t4 = fmaxf(fmaxf(p[12], p[13]), p[14]);
      float tm = fmaxf(fmaxf(fmaxf(t0, t1), t2), fmaxf(fmaxf(t3, t4), p[15]));
      tm = fmaxf(tm, __shfl_xor(tm, 16));
      tm = fmaxf(tm, __shfl_xor(tm, 32));
      if (!__all(tm <= m[j] + 11.0f)) {
        float nm = fmaxf(m[j], tm);
        float alpha = __builtin_exp2f(m[j] - nm);
        lsum[j] *= alpha;
#pragma unroll
        for (int dt = 0; dt < 4; ++dt) oacc[j][dt] *= alpha;
        m[j] = nm;
      }
#pragma unroll
      for (int i = 0; i < 16; ++i) p[i] = __builtin_exp2f(p[i] - m[j]);
      float a0 = (p[0] + p[1]) + (p[2] + p[3]);
      float a1 = (p[4] + p[5]) + (p[6] + p[7]);
      float a2 = (p[8] + p[9]) + (p[10] + p[11]);
      float a3 = (p[12] + p[13]) + (p[14] + p[15]);
      float ts = (a0 + a1) + (a2 + a3);
      ts += __shfl_xor(ts, 16);
      ts += __shfl_xor(ts, 32);
      lsum[j] += ts;
#pragma unroll
      for (int kb = 0; kb < 4; ++kb) {
        pbv[j][kb][0] = pkbf2(p[kb * 4 + 0], p[kb * 4 + 1]);
        pbv[j][kb][1] = pkbf2(p[kb * 4 + 2], p[kb * 4 + 3]);
      }
    }

    // ---- O^T += V^T * P^T via K=16 MFMA: va 8B reads shared, P direct from regs ----
    __builtin_amdgcn_s_setprio(1);
#pragma unroll
    for (int kb = 0; kb < 4; ++kb) {
#pragma unroll
      for (int dt = 0; dt < 4; ++dt) {
        u32x2 va = *reinterpret_cast<const u32x2*>(Vt + (dt * 16 + r16) * 128 + ((kb * 32 + g * 8) ^ kswz));
        oacc[0][dt] = mfma16(va, pbv[0][kb], oacc[0][dt]);
        oacc[1][dt] = mfma16(va, pbv[1][kb], oacc[1][dt]);
      }
    }
    __builtin_amdgcn_s_setprio(0);
    __syncthreads();
  }

  // epilogue: stream j rows l0 + j*64; lane holds O^T[d=dt*16+g*4+r][q=r16]
#pragma unroll
  for (int j = 0; j < 2; ++j) {
    const float inv = 1.0f / lsum[j];
    const size_t orow = (size_t)(b * LL + l0 + j * 64 + r16) * 1024 + h * 64;
#pragma unroll
    for (int dt = 0; dt < 4; ++dt) {
      ushort4 pk;
      pk.x = f2bf(oacc[j][dt][0] * inv); pk.y = f2bf(oacc[j][dt][1] * inv);
      pk.z = f2bf(oacc[j][dt][2] * inv); pk.w = f2bf(oacc[j][dt][3] * inv);
      *reinterpret_cast<ushort4*>(ob + orow + dt * 16 + g * 4) = pk;
    }
  }
}

// ---------------- launch ----------------
extern "C" void kernel_launch(void* const* d_in, const int* in_sizes, int n_in,
                              void* d_out, int out_size, void* d_ws, size_t ws_size,
                              hipStream_t stream) {
  const float* x     = (const float*)d_in[0];
  const float* pe    = (const float*)d_in[1];
  const float* Wq    = (const float*)d_in[2];
  const float* Wkv   = (const float*)d_in[3];
  const float* Wproj = (const float*)d_in[4];
  const float* bproj = (const float*)d_in[5];
  const float* qs    = (const float*)d_in[6];
  const float* ks    = (const float*)d_in[7];
  float* out = (float*)d_out;

  char* ws = (char*)d_ws;
  unsigned short* xb     = (unsigned short*)(ws);                        //  8MB x bf16
  unsigned short* Wall   = (unsigned short*)(ws + 8u  * 1024 * 1024);    //  6MB [Wq;Wkv]
  unsigned short* Wprojb = (unsigned short*)(ws + 14u * 1024 * 1024);    //  2MB
  unsigned short* qk     = (unsigned short*)(ws + 16u * 1024 * 1024);    // [4096][2048] 16MB
  unsigned short* vT     = (unsigned short*)(ws + 32u * 1024 * 1024);    // [32*64][2048] 8MB
  unsigned short* ob     = (unsigned short*)(ws + 40u * 1024 * 1024);    // [4096][1024] 8MB

  k_cast_all<<<4096, 256, 0, stream>>>(x, Wq, Wkv, Wproj, xb, Wall, Wprojb);
  k_gemm_qkv<<<dim3(32, 24), 256, 0, stream>>>(xb, Wall, qk, vT, pe, qs, ks);
  k_flash<<<512, 256, 0, stream>>>(qk, vT, ob);
  k_gemm_proj<<<dim3(64, 8), 256, 0, stream>>>(ob, Wprojb, out, bproj);
}